// Round 3
// baseline (284.768 us; speedup 1.0000x reference)
//
#include <hip/hip_runtime.h>

typedef unsigned int u32;
typedef unsigned long long u64;
typedef unsigned short u16;

#define DEV __device__ __forceinline__

// ---------- helpers ----------
DEV u16 f2bf(float x) {                      // fp32 -> bf16 RNE
  u32 u = __float_as_uint(x);
  u32 r = u + 0x7fffu + ((u >> 16) & 1u);
  return (u16)(r >> 16);
}
DEV float bflo(u32 d) { return __uint_as_float(d << 16); }
DEV float bfhi(u32 d) { return __uint_as_float(d & 0xffff0000u); }
DEV u64 sortable64(double f) {               // monotonic f64 -> u64
  long long b = __double_as_longlong(f);
  return (u64)b ^ (u64)((b >> 63) | (long long)0x8000000000000000ll);
}
// fp32 screening distance (pass A/B only; selection is fp64)
DEV float refdist(float qd2, float cd2, float cx, float cy, float cz,
                  float qx, float qy, float qz) {
  float dot = __builtin_fmaf(cz, qz, __builtin_fmaf(cy, qy, __fmul_rn(cx, qx)));
  return __fsub_rn(__fadd_rn(qd2, cd2), __fmul_rn(2.0f, dot));
}
DEV float sq3(float x, float y, float z) {
  return __fadd_rn(__fadd_rn(__fmul_rn(x, x), __fmul_rn(y, y)), __fmul_rn(z, z));
}
// fp64 exact-selection distance (float products are exact in f64)
DEV double ddist(double qx, double qy, double qz, double qd2,
                 float mxf, float myf, float mzf) {
  double cx = (double)mxf, cy = (double)myf, cz = (double)mzf;
  double cd2 = cx * cx + cy * cy + cz * cz;
  double dot = cx * qx + cy * qy + cz * qz;
  return (qd2 + cd2) - 2.0 * dot;
}

#define NB 2
#define NN 8192
#define NC 128
#define KK 21
#define MARGIN 1e-3f

// ---------- K0: fold BN into weights ----------
__global__ __launch_bounds__(256) void k_prep(
    const float* __restrict__ Wf, const float* __restrict__ gf, const float* __restrict__ bf_,
    const float* __restrict__ mf, const float* __restrict__ vf,
    const float* __restrict__ Wg, const float* __restrict__ gg, const float* __restrict__ bg,
    const float* __restrict__ mg, const float* __restrict__ vg,
    u16* __restrict__ Wt, float* __restrict__ beta_f,
    float* __restrict__ Wgu, float* __restrict__ Wgv, float* __restrict__ beta_g) {
  int g = blockIdx.x * 256 + threadIdx.x;     // 0..32767
  int c = g >> 8, o = g & 255;
  float val;
  if (o < 128) {
    float inv = gf[o] / sqrtf(vf[o] + 1e-5f);
    val = inv * (Wf[o * 256 + c] - Wf[o * 256 + c + 128]);
  } else {
    int o2 = o - 128;
    float inv = gf[o2] / sqrtf(vf[o2] + 1e-5f);
    val = inv * Wf[o2 * 256 + c + 128];
  }
  Wt[c * 256 + o] = f2bf(val);
  if (g < 128) {
    float inv = gf[g] / sqrtf(vf[g] + 1e-5f);
    beta_f[g] = bf_[g] - mf[g] * inv;
  } else if (g < 256) {
    int oo = g - 128;
    float invg = gg[oo] / sqrtf(vg[oo] + 1e-5f);
#pragma unroll
    for (int d = 0; d < 3; ++d) {
      Wgu[oo * 3 + d] = invg * (Wg[oo * 6 + d] - Wg[oo * 6 + 3 + d]);
      Wgv[oo * 3 + d] = invg * Wg[oo * 6 + 3 + d];
    }
    beta_g[oo] = bg[oo] - mg[oo] * invg;
  }
}

// ---------- K1geo ----------
__global__ __launch_bounds__(256) void k_geo(
    const float* __restrict__ xyz, const float* __restrict__ Wgu, const float* __restrict__ Wgv,
    const float* __restrict__ beta_g, u32* __restrict__ ucat, u32* __restrict__ vcat) {
  int g = blockIdx.x * 256 + threadIdx.x;     // < 16384*64
  int p = g >> 6, oc = g & 63;
  const float* xp = xyz + p * 3;
  float X = xp[0], Y = xp[1], Z = xp[2];
  u32 du = 0, dv = 0;
#pragma unroll
  for (int h = 0; h < 2; ++h) {
    int o = oc * 2 + h;
    float ug = X * Wgu[o * 3] + Y * Wgu[o * 3 + 1] + Z * Wgu[o * 3 + 2] + beta_g[o];
    float vv = X * Wgv[o * 3] + Y * Wgv[o * 3 + 1] + Z * Wgv[o * 3 + 2];
    du |= (u32)f2bf(ug) << (16 * h);
    dv |= (u32)f2bf(vv) << (16 * h);
  }
  ucat[p * 128 + oc] = du;
  vcat[p * 128 + oc] = dv;
}

// ---------- K1f: feat branch GEMM ----------
__global__ __launch_bounds__(256) void k_feat(
    const float* __restrict__ f, const u32* __restrict__ Wt32, const float* __restrict__ beta_f,
    u32* __restrict__ ucat, u32* __restrict__ vcat) {
  __shared__ u32 sW[128 * 128];
  __shared__ float sF[128][68];

  const int t = threadIdx.x;
  const int b = blockIdx.x >> 7;
  const int n0 = (blockIdx.x & 127) << 6;
  const int boff = b * (NC * NN);

#pragma unroll
  for (int k = 0; k < 64; ++k) sW[t + (k << 8)] = Wt32[t + (k << 8)];
#pragma unroll
  for (int k = 0; k < 32; ++k) {
    int i = t + (k << 8);
    int c = i >> 6, col = i & 63;
    sF[c][col] = f[boff + c * NN + n0 + col];
  }
  __syncthreads();

  const int w = t >> 6, lane = t & 63;
  const int og = lane >> 3, pg = lane & 7;
  const int o0 = w * 64 + og * 8;
  const int p0 = pg * 8;

  float acc[8][8];
#pragma unroll
  for (int a = 0; a < 8; ++a)
#pragma unroll
    for (int p = 0; p < 8; ++p) acc[a][p] = 0.0f;

  for (int c = 0; c < 128; ++c) {
    float4 fa = *(const float4*)&sF[c][p0];
    float4 fb = *(const float4*)&sF[c][p0 + 4];
    uint4 wr = *(const uint4*)&sW[c * 128 + (o0 >> 1)];
    float wv[8] = {bflo(wr.x), bfhi(wr.x), bflo(wr.y), bfhi(wr.y),
                   bflo(wr.z), bfhi(wr.z), bflo(wr.w), bfhi(wr.w)};
    float fv[8] = {fa.x, fa.y, fa.z, fa.w, fb.x, fb.y, fb.z, fb.w};
#pragma unroll
    for (int a = 0; a < 8; ++a)
#pragma unroll
      for (int p = 0; p < 8; ++p) acc[a][p] = __builtin_fmaf(wv[a], fv[p], acc[a][p]);
  }

  const int ochan = o0 & 127;
  const bool is_u = (o0 < 128);
  float bet[8];
#pragma unroll
  for (int a = 0; a < 8; ++a) bet[a] = is_u ? beta_f[ochan + a] : 0.0f;
  u32* dstbase = is_u ? ucat : vcat;
#pragma unroll
  for (int p = 0; p < 8; ++p) {
    int pt = (b << 13) + n0 + p0 + p;
    u32 d0 = (u32)f2bf(acc[0][p] + bet[0]) | ((u32)f2bf(acc[1][p] + bet[1]) << 16);
    u32 d1 = (u32)f2bf(acc[2][p] + bet[2]) | ((u32)f2bf(acc[3][p] + bet[3]) << 16);
    u32 d2 = (u32)f2bf(acc[4][p] + bet[4]) | ((u32)f2bf(acc[5][p] + bet[5]) << 16);
    u32 d3 = (u32)f2bf(acc[6][p] + bet[6]) | ((u32)f2bf(acc[7][p] + bet[7]) << 16);
    *(uint4*)&dstbase[pt * 128 + 64 + (ochan >> 1)] = make_uint4(d0, d1, d2, d3);
  }
}

// ---------- K2: exact KNN (k=21), fp32 screen + fp64 exact selection ----------
__global__ __launch_bounds__(256) void k_knn(const float* __restrict__ xyz,
                                             int* __restrict__ knn) {
  __shared__ float sx[NN];
  __shared__ float sy[NN];
  __shared__ float sz[NN];
  __shared__ u32 scnt[64];
  __shared__ u32 ssurv[64][128];

  const int t = threadIdx.x;
  const int b = blockIdx.x >> 7;
  const int n0 = (blockIdx.x & 127) << 6;

  const float4* g4 = (const float4*)(xyz + b * (NN * 3));
#pragma unroll
  for (int i = 0; i < 24; ++i) {
    int e4 = t + (i << 8);
    float4 v = g4[e4];
    float vv[4] = {v.x, v.y, v.z, v.w};
    int e = e4 << 2;
#pragma unroll
    for (int j = 0; j < 4; ++j) {
      int ee = e + j;
      int pt = (ee * 21846) >> 16;            // exact /3 for ee < 24576
      int comp = ee - pt * 3;
      float* dst = (comp == 0) ? sx : (comp == 1) ? sy : sz;
      dst[pt] = vv[j];
    }
  }
  if (t < 64) scnt[t] = 0u;
  __syncthreads();

  const int wave = t >> 6, lane = t & 63;
  const int qb = wave << 4;                   // 16 queries per wave

  float qx[16], qy[16], qz[16], qd2[16];
#pragma unroll
  for (int i = 0; i < 16; ++i) {
    int q = n0 + qb + i;
    qx[i] = sx[q]; qy[i] = sy[q]; qz[i] = sz[q];
    qd2[i] = sq3(qx[i], qy[i], qz[i]);
  }

  const float4* fx = (const float4*)sx;
  const float4* fy = (const float4*)sy;
  const float4* fz = (const float4*)sz;

  // ---- pass A: per-lane running min per query (fp32) ----
  float mn[16];
#pragma unroll
  for (int i = 0; i < 16; ++i) mn[i] = __builtin_inff();

  for (int tile = 0; tile < 32; ++tile) {
    float4 xv = fx[(tile << 6) + lane];
    float4 yv = fy[(tile << 6) + lane];
    float4 zv = fz[(tile << 6) + lane];
    float cx[4] = {xv.x, xv.y, xv.z, xv.w};
    float cy[4] = {yv.x, yv.y, yv.z, yv.w};
    float cz[4] = {zv.x, zv.y, zv.z, zv.w};
    float cd[4];
#pragma unroll
    for (int j = 0; j < 4; ++j) cd[j] = sq3(cx[j], cy[j], cz[j]);
#pragma unroll
    for (int i = 0; i < 16; ++i) {
#pragma unroll
      for (int j = 0; j < 4; ++j) {
        float s = refdist(qd2[i], cd[j], cx[j], cy[j], cz[j], qx[i], qy[i], qz[i]);
        mn[i] = fminf(mn[i], s);
      }
    }
  }

  // ---- threshold: 21st smallest of 64 lane minima (upper bound on d21) ----
  float thr[16];
#pragma unroll
  for (int i = 0; i < 16; ++i) {
    float v = mn[i];
#pragma unroll
    for (int k = 2; k <= 64; k <<= 1) {
#pragma unroll
      for (int j = k >> 1; j > 0; j >>= 1) {
        float p = __shfl_xor(v, j);
        bool takeMin = (((lane & k) == 0) == ((lane & j) == 0));
        v = takeMin ? fminf(v, p) : fmaxf(v, p);
      }
    }
    // +MARGIN: guarantees the fp64 top-21 set survives fp32 screening
    thr[i] = __shfl(v, 20) + MARGIN;
  }

  // ---- pass B: compact survivors (s <= thr) ----
  for (int tile = 0; tile < 32; ++tile) {
    float4 xv = fx[(tile << 6) + lane];
    float4 yv = fy[(tile << 6) + lane];
    float4 zv = fz[(tile << 6) + lane];
    float cx[4] = {xv.x, xv.y, xv.z, xv.w};
    float cy[4] = {yv.x, yv.y, yv.z, yv.w};
    float cz[4] = {zv.x, zv.y, zv.z, zv.w};
    float cd[4];
#pragma unroll
    for (int j = 0; j < 4; ++j) cd[j] = sq3(cx[j], cy[j], cz[j]);
    int mbase = (tile << 8) + (lane << 2);
#pragma unroll
    for (int i = 0; i < 16; ++i) {
      int qq = qb + i;
#pragma unroll
      for (int j = 0; j < 4; ++j) {
        float s = refdist(qd2[i], cd[j], cx[j], cy[j], cz[j], qx[i], qy[i], qz[i]);
        if (s <= thr[i]) {
          u32 slot = atomicAdd(&scnt[qq], 1u);
          if (slot < 128u) ssurv[qq][slot] = (u32)(mbase + j);
        }
      }
    }
  }

  // ---- selection: exact top-21 by fp64 (dist, idx) ----
#pragma unroll 1
  for (int i = 0; i < 16; ++i) {
    const int qq = qb + i;
    const int q = n0 + qq;
    double Qx = (double)sx[q], Qy = (double)sy[q], Qz = (double)sz[q];
    double Qd2 = Qx * Qx + Qy * Qy + Qz * Qz;
    u32 cnt = scnt[qq];
    int* outp = knn + ((b << 13) + q) * KK;

    bool v0 = ((u32)lane < cnt);
    u32 m0 = v0 ? (ssurv[qq][lane] & 8191u) : 0u;
    double s0 = ddist(Qx, Qy, Qz, Qd2, sx[m0], sy[m0], sz[m0]);
    // key: fp64-sortable, low 13 bits replaced by idx (lowest-index tie-break)
    u64 k0 = v0 ? ((sortable64(s0) & 0xFFFFFFFFFFFFE000ull) | (u64)m0) : ~0ull;

    if (cnt <= 64u) {
      u64 v = k0;
#pragma unroll
      for (int k = 2; k <= 64; k <<= 1) {
#pragma unroll
        for (int j = k >> 1; j > 0; j >>= 1) {
          u64 p = __shfl_xor(v, j);
          bool takeMin = (((lane & k) == 0) == ((lane & j) == 0));
          bool pl = p < v;
          u64 mnv = pl ? p : v;
          u64 mxv = pl ? v : p;
          v = takeMin ? mnv : mxv;
        }
      }
      if (lane < KK) outp[lane] = (int)(v & 8191ull);
    } else {
      bool v1 = ((u32)(lane + 64) < cnt);
      u32 m1 = v1 ? (ssurv[qq][lane + 64] & 8191u) : 0u;
      double s1 = ddist(Qx, Qy, Qz, Qd2, sx[m1], sy[m1], sz[m1]);
      u64 k1 = v1 ? ((sortable64(s1) & 0xFFFFFFFFFFFFE000ull) | (u64)m1) : ~0ull;
      u32 selm = 0;
      for (int r = 0; r < KK; ++r) {
        u64 mk = (k0 < k1) ? k0 : k1;
#pragma unroll
        for (int j = 32; j > 0; j >>= 1) {
          u64 p = __shfl_xor(mk, j);
          if (p < mk) mk = p;
        }
        if (k0 == mk) k0 = ~0ull;
        else if (k1 == mk) k1 = ~0ull;
        if (lane == r) selm = (u32)(mk & 8191ull);
      }
      if (lane < KK) outp[lane] = (int)selm;
    }
  }
}

// ---------- K3: gather + max + relu + transpose-write ----------
__global__ __launch_bounds__(256) void k_gather(
    const u32* __restrict__ ucat, const u32* __restrict__ vcat,
    const int* __restrict__ knn, float* __restrict__ out) {
  __shared__ float tr[64 * 258];

  const int t = threadIdx.x;
  const int b = blockIdx.x >> 7;
  const int n0 = (blockIdx.x & 127) << 6;
  const int w = t >> 6, lane = t & 63;
  const int which = w >> 1;
  const int lo = ((w & 1) << 6) | lane;

  for (int step = 0; step < 32; ++step) {
    int qq = step * 2 + which;
    int q = n0 + qq;
    const int* ip = knn + ((b << 13) + q) * KK;
    float a0 = -__builtin_inff(), a1 = -__builtin_inff();
#pragma unroll
    for (int k = 0; k < KK; ++k) {
      int p = ip[k];
      u32 d = vcat[(((b << 13) + p) << 7) + lo];
      a0 = fmaxf(a0, bflo(d));
      a1 = fmaxf(a1, bfhi(d));
    }
    u32 u = ucat[(((b << 13) + q) << 7) + lo];
    float r0 = fmaxf(bflo(u) + a0, 0.0f);
    float r1 = fmaxf(bfhi(u) + a1, 0.0f);
    *(float2*)&tr[qq * 258 + 2 * lo] = make_float2(r0, r1);
  }
  __syncthreads();

  float* ob = out + b * (256 * NN);
  for (int i = 0; i < 64; ++i) {
    int o = (w << 6) + i;
    ob[o * NN + n0 + lane] = tr[lane * 258 + o];
  }
}

// ---------- launch ----------
extern "C" void kernel_launch(void* const* d_in, const int* in_sizes, int n_in,
                              void* d_out, int out_size, void* d_ws, size_t ws_size,
                              hipStream_t stream) {
  const float* xyz = (const float*)d_in[0];
  const float* f   = (const float*)d_in[1];
  const float* Wg  = (const float*)d_in[2];
  const float* gg  = (const float*)d_in[3];
  const float* bg  = (const float*)d_in[4];
  const float* mg  = (const float*)d_in[5];
  const float* vg  = (const float*)d_in[6];
  const float* Wf  = (const float*)d_in[7];
  const float* gf  = (const float*)d_in[8];
  const float* bf_ = (const float*)d_in[9];
  const float* mf  = (const float*)d_in[10];
  const float* vf  = (const float*)d_in[11];

  char* ws = (char*)d_ws;
  u16*   Wt     = (u16*)ws;                               // 65536 B
  float* beta_f = (float*)(ws + 65536);
  float* Wgu    = (float*)(ws + 66048);
  float* Wgv    = (float*)(ws + 67584);
  float* beta_g = (float*)(ws + 69120);
  u32*   ucat   = (u32*)(ws + 69632);                     // 8 MB
  u32*   vcat   = (u32*)(ws + 69632 + 8388608);           // 8 MB
  int*   knn    = (int*)(ws + 69632 + 2 * 8388608);       // 1.4 MB
  float* out    = (float*)d_out;

  if (ws_size < (size_t)(69632 + 2 * 8388608 + 16384 * KK * 4)) return;

  k_prep<<<dim3(128), dim3(256), 0, stream>>>(Wf, gf, bf_, mf, vf, Wg, gg, bg, mg, vg,
                                              Wt, beta_f, Wgu, Wgv, beta_g);
  k_geo<<<dim3(4096), dim3(256), 0, stream>>>(xyz, Wgu, Wgv, beta_g, ucat, vcat);
  k_feat<<<dim3(256), dim3(256), 0, stream>>>(f, (const u32*)Wt, beta_f, ucat, vcat);
  k_knn<<<dim3(256), dim3(256), 0, stream>>>(xyz, knn);
  k_gather<<<dim3(256), dim3(256), 0, stream>>>(ucat, vcat, knn, out);
}

// Round 4
// 194.165 us; speedup vs baseline: 1.4666x; 1.4666x over previous
//
#include <hip/hip_runtime.h>

typedef unsigned int u32;
typedef unsigned long long u64;
typedef unsigned short u16;

#define DEV __device__ __forceinline__

// ---------- helpers ----------
DEV u16 f2bf(float x) {                      // fp32 -> bf16 RNE
  u32 u = __float_as_uint(x);
  u32 r = u + 0x7fffu + ((u >> 16) & 1u);
  return (u16)(r >> 16);
}
DEV float bflo(u32 d) { return __uint_as_float(d << 16); }
DEV float bfhi(u32 d) { return __uint_as_float(d & 0xffff0000u); }
DEV u64 sortable64(double f) {               // monotonic f64 -> u64
  long long b = __double_as_longlong(f);
  return (u64)b ^ (u64)((b >> 63) | (long long)0x8000000000000000ll);
}
// fp64 exact-selection distance (float products are exact in f64)
DEV double ddist(double qx, double qy, double qz, double qd2,
                 float mxf, float myf, float mzf) {
  double cx = (double)mxf, cy = (double)myf, cz = (double)mzf;
  double cd2 = cx * cx + cy * cy + cz * cz;
  double dot = cx * qx + cy * qy + cz * qz;
  return (qd2 + cd2) - 2.0 * dot;
}

#define NB 2
#define NN 8192
#define NC 128
#define KK 21
// screening metric: st = cd2 - 2*dot (qd2 dropped — per-query constant shift).
// fp32 error vs fp64 <= ~2e-4 on these operand scales; MARGIN covers it so the
// fp64 top-21 set provably survives fp32 screening.
#define MARGIN 1e-3f
#define CT 2048                              // candidate tile size

// ---------- K0: fold BN into weights ----------
__global__ __launch_bounds__(256) void k_prep(
    const float* __restrict__ Wf, const float* __restrict__ gf, const float* __restrict__ bf_,
    const float* __restrict__ mf, const float* __restrict__ vf,
    const float* __restrict__ Wg, const float* __restrict__ gg, const float* __restrict__ bg,
    const float* __restrict__ mg, const float* __restrict__ vg,
    u16* __restrict__ Wt, float* __restrict__ beta_f,
    float* __restrict__ Wgu, float* __restrict__ Wgv, float* __restrict__ beta_g) {
  int g = blockIdx.x * 256 + threadIdx.x;     // 0..32767
  int c = g >> 8, o = g & 255;
  float val;
  if (o < 128) {
    float inv = gf[o] / sqrtf(vf[o] + 1e-5f);
    val = inv * (Wf[o * 256 + c] - Wf[o * 256 + c + 128]);
  } else {
    int o2 = o - 128;
    float inv = gf[o2] / sqrtf(vf[o2] + 1e-5f);
    val = inv * Wf[o2 * 256 + c + 128];
  }
  Wt[c * 256 + o] = f2bf(val);
  if (g < 128) {
    float inv = gf[g] / sqrtf(vf[g] + 1e-5f);
    beta_f[g] = bf_[g] - mf[g] * inv;
  } else if (g < 256) {
    int oo = g - 128;
    float invg = gg[oo] / sqrtf(vg[oo] + 1e-5f);
#pragma unroll
    for (int d = 0; d < 3; ++d) {
      Wgu[oo * 3 + d] = invg * (Wg[oo * 6 + d] - Wg[oo * 6 + 3 + d]);
      Wgv[oo * 3 + d] = invg * Wg[oo * 6 + 3 + d];
    }
    beta_g[oo] = bg[oo] - mg[oo] * invg;
  }
}

// ---------- K1geo ----------
__global__ __launch_bounds__(256) void k_geo(
    const float* __restrict__ xyz, const float* __restrict__ Wgu, const float* __restrict__ Wgv,
    const float* __restrict__ beta_g, u32* __restrict__ ucat, u32* __restrict__ vcat) {
  int g = blockIdx.x * 256 + threadIdx.x;     // < 16384*64
  int p = g >> 6, oc = g & 63;
  const float* xp = xyz + p * 3;
  float X = xp[0], Y = xp[1], Z = xp[2];
  u32 du = 0, dv = 0;
#pragma unroll
  for (int h = 0; h < 2; ++h) {
    int o = oc * 2 + h;
    float ug = X * Wgu[o * 3] + Y * Wgu[o * 3 + 1] + Z * Wgu[o * 3 + 2] + beta_g[o];
    float vv = X * Wgv[o * 3] + Y * Wgv[o * 3 + 1] + Z * Wgv[o * 3 + 2];
    du |= (u32)f2bf(ug) << (16 * h);
    dv |= (u32)f2bf(vv) << (16 * h);
  }
  ucat[p * 128 + oc] = du;
  vcat[p * 128 + oc] = dv;
}

// ---------- K1f: feat branch GEMM ----------
__global__ __launch_bounds__(256) void k_feat(
    const float* __restrict__ f, const u32* __restrict__ Wt32, const float* __restrict__ beta_f,
    u32* __restrict__ ucat, u32* __restrict__ vcat) {
  __shared__ u32 sW[128 * 128];
  __shared__ float sF[128][68];

  const int t = threadIdx.x;
  const int b = blockIdx.x >> 7;
  const int n0 = (blockIdx.x & 127) << 6;
  const int boff = b * (NC * NN);

#pragma unroll
  for (int k = 0; k < 64; ++k) sW[t + (k << 8)] = Wt32[t + (k << 8)];
#pragma unroll
  for (int k = 0; k < 32; ++k) {
    int i = t + (k << 8);
    int c = i >> 6, col = i & 63;
    sF[c][col] = f[boff + c * NN + n0 + col];
  }
  __syncthreads();

  const int w = t >> 6, lane = t & 63;
  const int og = lane >> 3, pg = lane & 7;
  const int o0 = w * 64 + og * 8;
  const int p0 = pg * 8;

  float acc[8][8];
#pragma unroll
  for (int a = 0; a < 8; ++a)
#pragma unroll
    for (int p = 0; p < 8; ++p) acc[a][p] = 0.0f;

  for (int c = 0; c < 128; ++c) {
    float4 fa = *(const float4*)&sF[c][p0];
    float4 fb = *(const float4*)&sF[c][p0 + 4];
    uint4 wr = *(const uint4*)&sW[c * 128 + (o0 >> 1)];
    float wv[8] = {bflo(wr.x), bfhi(wr.x), bflo(wr.y), bfhi(wr.y),
                   bflo(wr.z), bfhi(wr.z), bflo(wr.w), bfhi(wr.w)};
    float fv[8] = {fa.x, fa.y, fa.z, fa.w, fb.x, fb.y, fb.z, fb.w};
#pragma unroll
    for (int a = 0; a < 8; ++a)
#pragma unroll
      for (int p = 0; p < 8; ++p) acc[a][p] = __builtin_fmaf(wv[a], fv[p], acc[a][p]);
  }

  const int ochan = o0 & 127;
  const bool is_u = (o0 < 128);
  float bet[8];
#pragma unroll
  for (int a = 0; a < 8; ++a) bet[a] = is_u ? beta_f[ochan + a] : 0.0f;
  u32* dstbase = is_u ? ucat : vcat;
#pragma unroll
  for (int p = 0; p < 8; ++p) {
    int pt = (b << 13) + n0 + p0 + p;
    u32 d0 = (u32)f2bf(acc[0][p] + bet[0]) | ((u32)f2bf(acc[1][p] + bet[1]) << 16);
    u32 d1 = (u32)f2bf(acc[2][p] + bet[2]) | ((u32)f2bf(acc[3][p] + bet[3]) << 16);
    u32 d2 = (u32)f2bf(acc[4][p] + bet[4]) | ((u32)f2bf(acc[5][p] + bet[5]) << 16);
    u32 d3 = (u32)f2bf(acc[6][p] + bet[6]) | ((u32)f2bf(acc[7][p] + bet[7]) << 16);
    *(uint4*)&dstbase[pt * 128 + 64 + (ochan >> 1)] = make_uint4(d0, d1, d2, d3);
  }
}

// ---------- K2: exact KNN (k=21) — candidate-tiled, 16 queries/block ----------
// LDS ~37 KB -> 4 blocks/CU (16 waves/CU) vs old 131.5 KB (1 block/CU).
__global__ __launch_bounds__(256, 4) void k_knn(const float* __restrict__ xyz,
                                                int* __restrict__ knn) {
  __shared__ float4 sc[CT];                   // (x,y,z,d2) per candidate — 32 KB
  __shared__ u16 ssurv[16][128];              // 4 KB
  __shared__ u32 scnt[16];

  const int t = threadIdx.x;
  const int blk = blockIdx.x;                 // 0..1023
  const int b = blk >> 9;                     // 512 blocks per batch
  const int n0 = (blk & 511) << 4;            // 16 queries per block
  const float* X = xyz + b * (NN * 3);

  if (t < 16) scnt[t] = 0u;

  const int w = t >> 6, lane = t & 63;

  // query coords (4 queries per wave); fold -2x for the fma chain
  float mx[4], my[4], mz[4];
#pragma unroll
  for (int i = 0; i < 4; ++i) {
    int q = n0 + (w << 2) + i;
    mx[i] = -2.0f * X[q * 3];
    my[i] = -2.0f * X[q * 3 + 1];
    mz[i] = -2.0f * X[q * 3 + 2];
  }

  // ---- pass A: per-lane running min of st = cd2 - 2*dot ----
  float mn[4];
#pragma unroll
  for (int i = 0; i < 4; ++i) mn[i] = __builtin_inff();

  for (int ct = 0; ct < NN / CT; ++ct) {
    __syncthreads();                          // guard tile buffer reuse
    const float* Xt = X + ct * (CT * 3);
#pragma unroll
    for (int k = 0; k < 8; ++k) {
      int c = (k << 8) + t;
      float x = Xt[c * 3], y = Xt[c * 3 + 1], z = Xt[c * 3 + 2];
      float d2 = __builtin_fmaf(x, x, __builtin_fmaf(y, y, z * z));
      sc[c] = make_float4(x, y, z, d2);
    }
    __syncthreads();
#pragma unroll 4
    for (int cc = 0; cc < CT; cc += 64) {
      float4 C = sc[cc + lane];
#pragma unroll
      for (int i = 0; i < 4; ++i) {
        float s = __builtin_fmaf(C.x, mx[i],
                  __builtin_fmaf(C.y, my[i],
                  __builtin_fmaf(C.z, mz[i], C.w)));
        mn[i] = fminf(mn[i], s);
      }
    }
  }

  // ---- threshold: 21st smallest of 64 disjoint-subset lane minima ----
  // (any 21 of the minima witness 21 distinct candidates => upper bound on d21)
  float thr[4];
#pragma unroll
  for (int i = 0; i < 4; ++i) {
    float v = mn[i];
#pragma unroll
    for (int k = 2; k <= 64; k <<= 1) {
#pragma unroll
      for (int j = k >> 1; j > 0; j >>= 1) {
        float p = __shfl_xor(v, j);
        bool takeMin = (((lane & k) == 0) == ((lane & j) == 0));
        v = takeMin ? fminf(v, p) : fmaxf(v, p);
      }
    }
    thr[i] = __shfl(v, 20) + MARGIN;
  }

  // ---- pass B: compact survivors ----
  for (int ct = 0; ct < NN / CT; ++ct) {
    __syncthreads();
    const float* Xt = X + ct * (CT * 3);
#pragma unroll
    for (int k = 0; k < 8; ++k) {
      int c = (k << 8) + t;
      float x = Xt[c * 3], y = Xt[c * 3 + 1], z = Xt[c * 3 + 2];
      float d2 = __builtin_fmaf(x, x, __builtin_fmaf(y, y, z * z));
      sc[c] = make_float4(x, y, z, d2);
    }
    __syncthreads();
    int mbase = ct * CT + lane;
#pragma unroll 4
    for (int cc = 0; cc < CT; cc += 64) {
      float4 C = sc[cc + lane];
#pragma unroll
      for (int i = 0; i < 4; ++i) {
        float s = __builtin_fmaf(C.x, mx[i],
                  __builtin_fmaf(C.y, my[i],
                  __builtin_fmaf(C.z, mz[i], C.w)));
        if (s <= thr[i]) {
          int qq = (w << 2) + i;
          u32 slot = atomicAdd(&scnt[qq], 1u);
          if (slot < 128u) ssurv[qq][slot] = (u16)(mbase + cc);
        }
      }
    }
  }
  __syncthreads();

  // ---- selection: exact top-21 by fp64 (dist, idx) ----
#pragma unroll 1
  for (int i = 0; i < 4; ++i) {
    const int qq = (w << 2) + i;
    const int q = n0 + qq;
    double Qx = (double)X[q * 3], Qy = (double)X[q * 3 + 1], Qz = (double)X[q * 3 + 2];
    double Qd2 = Qx * Qx + Qy * Qy + Qz * Qz;
    u32 cnt = scnt[qq];
    int* outp = knn + ((b << 13) + q) * KK;

    bool v0 = ((u32)lane < cnt);
    u32 m0 = v0 ? (u32)ssurv[qq][lane] : 0u;
    double s0 = ddist(Qx, Qy, Qz, Qd2, X[m0 * 3], X[m0 * 3 + 1], X[m0 * 3 + 2]);
    // key: fp64-sortable, low 13 bits replaced by idx (lowest-index tie-break)
    u64 k0 = v0 ? ((sortable64(s0) & 0xFFFFFFFFFFFFE000ull) | (u64)m0) : ~0ull;

    if (cnt <= 64u) {
      u64 v = k0;
#pragma unroll
      for (int k = 2; k <= 64; k <<= 1) {
#pragma unroll
        for (int j = k >> 1; j > 0; j >>= 1) {
          u64 p = __shfl_xor(v, j);
          bool takeMin = (((lane & k) == 0) == ((lane & j) == 0));
          bool pl = p < v;
          u64 mnv = pl ? p : v;
          u64 mxv = pl ? v : p;
          v = takeMin ? mnv : mxv;
        }
      }
      if (lane < KK) outp[lane] = (int)(v & 8191ull);
    } else {
      bool v1 = ((u32)(lane + 64) < cnt);
      u32 m1 = v1 ? (u32)ssurv[qq][lane + 64] : 0u;
      double s1 = ddist(Qx, Qy, Qz, Qd2, X[m1 * 3], X[m1 * 3 + 1], X[m1 * 3 + 2]);
      u64 k1 = v1 ? ((sortable64(s1) & 0xFFFFFFFFFFFFE000ull) | (u64)m1) : ~0ull;
      u32 selm = 0;
      for (int r = 0; r < KK; ++r) {
        u64 mk = (k0 < k1) ? k0 : k1;
#pragma unroll
        for (int j = 32; j > 0; j >>= 1) {
          u64 p = __shfl_xor(mk, j);
          if (p < mk) mk = p;
        }
        if (k0 == mk) k0 = ~0ull;
        else if (k1 == mk) k1 = ~0ull;
        if (lane == r) selm = (u32)(mk & 8191ull);
      }
      if (lane < KK) outp[lane] = (int)selm;
    }
  }
}

// ---------- K3: gather + max + relu + transpose-write ----------
__global__ __launch_bounds__(256) void k_gather(
    const u32* __restrict__ ucat, const u32* __restrict__ vcat,
    const int* __restrict__ knn, float* __restrict__ out) {
  __shared__ float tr[64 * 258];

  const int t = threadIdx.x;
  const int b = blockIdx.x >> 7;
  const int n0 = (blockIdx.x & 127) << 6;
  const int w = t >> 6, lane = t & 63;
  const int which = w >> 1;
  const int lo = ((w & 1) << 6) | lane;

  for (int step = 0; step < 32; ++step) {
    int qq = step * 2 + which;
    int q = n0 + qq;
    const int* ip = knn + ((b << 13) + q) * KK;
    float a0 = -__builtin_inff(), a1 = -__builtin_inff();
#pragma unroll
    for (int k = 0; k < KK; ++k) {
      int p = ip[k];
      u32 d = vcat[(((b << 13) + p) << 7) + lo];
      a0 = fmaxf(a0, bflo(d));
      a1 = fmaxf(a1, bfhi(d));
    }
    u32 u = ucat[(((b << 13) + q) << 7) + lo];
    float r0 = fmaxf(bflo(u) + a0, 0.0f);
    float r1 = fmaxf(bfhi(u) + a1, 0.0f);
    *(float2*)&tr[qq * 258 + 2 * lo] = make_float2(r0, r1);
  }
  __syncthreads();

  float* ob = out + b * (256 * NN);
  for (int i = 0; i < 64; ++i) {
    int o = (w << 6) + i;
    ob[o * NN + n0 + lane] = tr[lane * 258 + o];
  }
}

// ---------- launch ----------
extern "C" void kernel_launch(void* const* d_in, const int* in_sizes, int n_in,
                              void* d_out, int out_size, void* d_ws, size_t ws_size,
                              hipStream_t stream) {
  const float* xyz = (const float*)d_in[0];
  const float* f   = (const float*)d_in[1];
  const float* Wg  = (const float*)d_in[2];
  const float* gg  = (const float*)d_in[3];
  const float* bg  = (const float*)d_in[4];
  const float* mg  = (const float*)d_in[5];
  const float* vg  = (const float*)d_in[6];
  const float* Wf  = (const float*)d_in[7];
  const float* gf  = (const float*)d_in[8];
  const float* bf_ = (const float*)d_in[9];
  const float* mf  = (const float*)d_in[10];
  const float* vf  = (const float*)d_in[11];

  char* ws = (char*)d_ws;
  u16*   Wt     = (u16*)ws;                               // 65536 B
  float* beta_f = (float*)(ws + 65536);
  float* Wgu    = (float*)(ws + 66048);
  float* Wgv    = (float*)(ws + 67584);
  float* beta_g = (float*)(ws + 69120);
  u32*   ucat   = (u32*)(ws + 69632);                     // 8 MB
  u32*   vcat   = (u32*)(ws + 69632 + 8388608);           // 8 MB
  int*   knn    = (int*)(ws + 69632 + 2 * 8388608);       // 1.4 MB
  float* out    = (float*)d_out;

  if (ws_size < (size_t)(69632 + 2 * 8388608 + 16384 * KK * 4)) return;

  k_prep<<<dim3(128), dim3(256), 0, stream>>>(Wf, gf, bf_, mf, vf, Wg, gg, bg, mg, vg,
                                              Wt, beta_f, Wgu, Wgv, beta_g);
  k_geo<<<dim3(4096), dim3(256), 0, stream>>>(xyz, Wgu, Wgv, beta_g, ucat, vcat);
  k_feat<<<dim3(256), dim3(256), 0, stream>>>(f, (const u32*)Wt, beta_f, ucat, vcat);
  k_knn<<<dim3(1024), dim3(256), 0, stream>>>(xyz, knn);
  k_gather<<<dim3(256), dim3(256), 0, stream>>>(ucat, vcat, knn, out);
}